// Round 9
// baseline (350.827 us; speedup 1.0000x reference)
//
#include <hip/hip_runtime.h>
#include <cstddef>

#define A_  5
#define C_  12
#define RPG (C_ * A_)                 // (coil,a) planes = 60
#define TWO_PI 6.28318530717958647692f
#define NPAD 596                      // fftB array stride (R7-proven padding)

// ---------------------------------------------------------------------------
// Pipeline R8 (resubmit):
//   k_zero  : zero planar out (outfr accumulates atomically)
//   k_fft1c : per (ca, x-quad): mps*x, pad y, batch-4 y-FFTs (LDS fftB,
//             256 threads = 2 groups x 2 arrays), write bufA[ca][ky][x]
//   k_colfmc: per (coil,ky), 5 WAVES: wave w register-FFTs row ain=w
//             (wfft512, zero barriers inside), F spectra parked in LDS;
//             barrier; mix (threads own kx, K native+XCD-pinned, in-place);
//             barrier; wave w register-IFFTs ao=w, coalesced row stores.
//             2 barriers/block (R7: 13), 15 waves/CU (R7: 6).
//   k_outfr : per (a, x-quad, coil-triplet): batch-4 ky-IFFTs (256 thr),
//             crop y, conj(mps) reduce, atomicAdd into out
// R7 lesson: latency-bound => waves/CU is first-order, barrier count second.
// R6 lesson: F in registers starves the mix (84 VGPR); park F in LDS.
// ---------------------------------------------------------------------------
__device__ float2 g_bufA[RPG * 512 * 256];  // 63 MB [ca][ky][x]
__device__ float2 g_bufB[RPG * 512 * 256];  // 63 MB [ca][ky][x]

__device__ __forceinline__ int P5(int i) { return i + 5 * (i >> 5); }
__device__ __forceinline__ int PT(int i) { return i + (i >> 3); }

__device__ __forceinline__ void build_tab256(float2* tab, int t) {
    if (t < 256) {
        float s, c;
        __sincosf(-TWO_PI * (float)t * (1.0f / 512.0f), &s, &c);
        tab[PT(t)] = make_float2(c, s);
    }
}

template<int DIR>
__device__ __forceinline__ float2 cmulw(float2 v, float2 w) {
    float cv = w.x, sv = (DIR < 0) ? w.y : -w.y;   // DIR=+1 -> conj(w)
    return make_float2(v.x * cv - v.y * sv, v.x * sv + v.y * cv);
}

// ---- in-register 8-point DFT (R6-proven, verbatim) ----
template<int DIR>
__device__ __forceinline__ void dft8(float* xr, float* xi) {
    const float S = 0.70710678118654752f;
    float ar[4], ai[4], br[4], bi[4];
#pragma unroll
    for (int j = 0; j < 4; ++j) {
        ar[j] = xr[j] + xr[j+4]; ai[j] = xi[j] + xi[j+4];
        br[j] = xr[j] - xr[j+4]; bi[j] = xi[j] - xi[j+4];
    }
    float t;
    if (DIR < 0) {
        t = S*(br[1]+bi[1]); bi[1] = S*(bi[1]-br[1]); br[1] = t;
        t = bi[2];           bi[2] = -br[2];          br[2] = t;
        t = S*(bi[3]-br[3]); bi[3] = -S*(br[3]+bi[3]); br[3] = t;
    } else {
        t = S*(br[1]-bi[1]); bi[1] = S*(bi[1]+br[1]); br[1] = t;
        t = -bi[2];          bi[2] = br[2];           br[2] = t;
        t = -S*(br[3]+bi[3]); bi[3] = S*(br[3]-bi[3]); br[3] = t;
    }
    float c0r=ar[0]+ar[2], c0i=ai[0]+ai[2], c1r=ar[1]+ar[3], c1i=ai[1]+ai[3];
    float d0r=ar[0]-ar[2], d0i=ai[0]-ai[2], d1r, d1i;
    if (DIR < 0) { d1r =  ai[1]-ai[3]; d1i = -(ar[1]-ar[3]); }
    else         { d1r = -(ai[1]-ai[3]); d1i =  ar[1]-ar[3]; }
    xr[0]=c0r+c1r; xi[0]=c0i+c1i; xr[4]=c0r-c1r; xi[4]=c0i-c1i;
    xr[2]=d0r+d1r; xi[2]=d0i+d1i; xr[6]=d0r-d1r; xi[6]=d0i-d1i;
    c0r=br[0]+br[2]; c0i=bi[0]+bi[2]; c1r=br[1]+br[3]; c1i=bi[1]+bi[3];
    d0r=br[0]-br[2]; d0i=bi[0]-bi[2];
    if (DIR < 0) { d1r =  bi[1]-bi[3]; d1i = -(br[1]-br[3]); }
    else         { d1r = -(bi[1]-bi[3]); d1i =  br[1]-br[3]; }
    xr[1]=c0r+c1r; xi[1]=c0i+c1i; xr[5]=c0r-c1r; xi[5]=c0i-c1i;
    xr[3]=d0r+d1r; xi[3]=d0i+d1i; xr[7]=d0r-d1r; xi[7]=d0i-d1i;
}

__device__ __forceinline__ void twiddle_chain(float* vr, float* vi, float ang) {
    float s, c; __sincosf(ang, &s, &c);
    float twr = c, twi = s;
#pragma unroll
    for (int d = 1; d < 8; ++d) {
        float tr = vr[d]*twr - vi[d]*twi;
        vi[d]    = vr[d]*twi + vi[d]*twr;
        vr[d]    = tr;
        float nr = twr*c - twi*s;
        twi      = twr*s + twi*c;
        twr      = nr;
    }
}

// Wave-synchronous 512-pt FFT (R6-proven, verbatim). Input: reg a = X[64a+lh].
// Output: reg g = Y[64g + 8*(lh&7) + (lh>>3)]. sre/sim per-wave scratch 576.
template<int DIR>
__device__ __forceinline__ void wfft512(float* vr, float* vi,
                                        float* sre, float* sim, int lh) {
    const float sgn = (DIR < 0) ? -1.f : 1.f;
    dft8<DIR>(vr, vi);
    twiddle_chain(vr, vi, sgn * (TWO_PI/512.f) * (float)lh);
#pragma unroll
    for (int d = 0; d < 8; ++d) { sre[72*d+lh] = vr[d]; sim[72*d+lh] = vi[d]; }
    asm volatile("s_waitcnt lgkmcnt(0)" ::: "memory");
    int rb = 72*(lh>>3) + (lh&7);
#pragma unroll
    for (int e = 0; e < 8; ++e) { vr[e] = sre[rb+8*e]; vi[e] = sim[rb+8*e]; }
    dft8<DIR>(vr, vi);
    twiddle_chain(vr, vi, sgn * (TWO_PI/64.f) * (float)(lh & 7));
    int wb = 9*(lh>>3) + (lh&7);
#pragma unroll
    for (int h = 0; h < 8; ++h) { sre[72*h+wb] = vr[h]; sim[72*h+wb] = vi[h]; }
    asm volatile("s_waitcnt lgkmcnt(0)" ::: "memory");
    int rb2 = 72*(lh&7) + 9*(lh>>3);
#pragma unroll
    for (int f = 0; f < 8; ++f) { vr[f] = sre[rb2+f]; vi[f] = sim[rb2+f]; }
    dft8<DIR>(vr, vi);
}

// Batched Stockham 512-pt FFT, 4 arrays, 256 threads (group t>>7 handles
// arrays {0,1} / {2,3}). Same per-array index math as R7 (proven). ~6 barriers.
template<int DIR>
__device__ void fftB4(float (*AR)[NPAD], float (*AI)[NPAD],
                      float (*BR)[NPAD], float (*BI)[NPAD],
                      const float2* tab, int t) {
    int tt = t & 127, b0 = (t >> 7) << 1;
    float (*sR)[NPAD] = AR; float (*sI)[NPAD] = AI;
    float (*dR)[NPAD] = BR; float (*dI)[NPAD] = BI;
    int Ns = 1;
    #pragma unroll
    for (int s = 0; s < 4; ++s) {
        __syncthreads();
        int m = tt & (Ns - 1);
        int e1 = m << (7 - 2 * s);
        float2 w1 = tab[PT(e1)], w2 = tab[PT(2 * e1)];
        float2 w3 = make_float2(w1.x * w2.x - w1.y * w2.y,
                                w1.x * w2.y + w1.y * w2.x);
        int i0 = P5(tt), i1 = P5(tt + 128), i2 = P5(tt + 256), i3 = P5(tt + 384);
        int idxD = ((tt & ~(Ns - 1)) << 2) | m;
        int o0 = P5(idxD), o1 = P5(idxD + Ns);
        int o2 = P5(idxD + 2 * Ns), o3 = P5(idxD + 3 * Ns);
        #pragma unroll
        for (int bb = 0; bb < 2; ++bb) {
            int b = b0 + bb;
            float2 v0 = make_float2(sR[b][i0], sI[b][i0]);
            float2 v1 = cmulw<DIR>(make_float2(sR[b][i1], sI[b][i1]), w1);
            float2 v2 = cmulw<DIR>(make_float2(sR[b][i2], sI[b][i2]), w2);
            float2 v3 = cmulw<DIR>(make_float2(sR[b][i3], sI[b][i3]), w3);
            float2 t0 = make_float2(v0.x + v2.x, v0.y + v2.y);
            float2 t1 = make_float2(v0.x - v2.x, v0.y - v2.y);
            float2 t2 = make_float2(v1.x + v3.x, v1.y + v3.y);
            float2 t3 = make_float2(v1.x - v3.x, v1.y - v3.y);
            float2 y0 = make_float2(t0.x + t2.x, t0.y + t2.y);
            float2 y2 = make_float2(t0.x - t2.x, t0.y - t2.y);
            float2 y1, y3;
            if (DIR < 0) {
                y1 = make_float2(t1.x + t3.y, t1.y - t3.x);
                y3 = make_float2(t1.x - t3.y, t1.y + t3.x);
            } else {
                y1 = make_float2(t1.x - t3.y, t1.y + t3.x);
                y3 = make_float2(t1.x + t3.y, t1.y - t3.x);
            }
            dR[b][o0] = y0.x; dI[b][o0] = y0.y;
            dR[b][o1] = y1.x; dI[b][o1] = y1.y;
            dR[b][o2] = y2.x; dI[b][o2] = y2.y;
            dR[b][o3] = y3.x; dI[b][o3] = y3.y;
        }
        { auto tp = sR; sR = dR; dR = tp; }
        { auto tp = sI; sI = dI; dI = tp; }
        Ns <<= 2;
    }
    __syncthreads();
    #pragma unroll
    for (int q = 0; q < 2; ++q) {
        int j2 = tt + q * 128;
        float2 w = tab[PT(j2)];
        int i0 = P5(j2), i1 = P5(j2 + 256);
        #pragma unroll
        for (int bb = 0; bb < 2; ++bb) {
            int b = b0 + bb;
            float2 v0 = make_float2(sR[b][i0], sI[b][i0]);
            float2 tw = cmulw<DIR>(make_float2(sR[b][i1], sI[b][i1]), w);
            dR[b][i0] = v0.x + tw.x; dI[b][i0] = v0.y + tw.y;
            dR[b][i1] = v0.x - tw.x; dI[b][i1] = v0.y - tw.y;
        }
    }
    __syncthreads();
}

// ---------------------------------------------------------------------------
__global__ void k_zero(float* __restrict__ out, int n) {
    int i = blockIdx.x * 256 + threadIdx.x;
    int stride = gridDim.x * 256;
    for (; i < n; i += stride) out[i] = 0.f;
}

// ---------------------------------------------------------------------------
// Pass 1: block = (ca, x-quad), 256 threads. Modulate mps*x, pad y, batch-4
// forward y-FFTs, write bufA[ca][ky][x0..x0+3] (32B chunks).
// ---------------------------------------------------------------------------
__global__ void __launch_bounds__(256) k_fft1c(const float* __restrict__ xr_,
        const float* __restrict__ xi_, const float* __restrict__ mr_,
        const float* __restrict__ mi_) {
    __shared__ float AR[4][NPAD], AI[4][NPAD], BR[4][NPAD], BI[4][NPAD];
    __shared__ float2 tab[288];
    int bid = blockIdx.x;
    int ca = bid >> 6;
    int x0 = (bid & 63) << 2;
    int coil = ca / A_, a = ca % A_;
    int t = threadIdx.x;
    build_tab256(tab, t);
    int xc = t & 3, yo = t >> 2;          // yo 0..63
    int xcol = x0 + xc;
    const float* xr = xr_ + a * 65536;
    const float* xi = xi_ + a * 65536;
    const float* mr = mr_ + coil * 65536;
    const float* mi = mi_ + coil * 65536;
    #pragma unroll
    for (int r = 0; r < 2; ++r) {         // zero pads y5 in [0,128)|[384,512)
        int z = yo + 64 * r;
        AR[xc][P5(z)] = 0.f;        AI[xc][P5(z)] = 0.f;
        AR[xc][P5(384 + z)] = 0.f;  AI[xc][P5(384 + z)] = 0.f;
    }
    #pragma unroll
    for (int r = 0; r < 4; ++r) {
        int y = yo + 64 * r;
        int idx = y * 256 + xcol;
        float xrv = xr[idx], xiv = xi[idx], mrv = mr[idx], miv = mi[idx];
        int p = P5(128 + y);
        AR[xc][p] = xrv * mrv - xiv * miv;
        AI[xc][p] = xrv * miv + xiv * mrv;
    }
    fftB4<-1>(AR, AI, BR, BI, tab, t);
    float2* o = g_bufA + (size_t)ca * 131072 + x0 + xc;
    #pragma unroll
    for (int rr = 0; rr < 8; ++rr) {
        int ky = yo + 64 * rr;
        int p = P5(ky);
        o[(size_t)ky * 256] = make_float2(BR[xc][p], BI[xc][p]);
    }
}

// ---------------------------------------------------------------------------
// Pass 2 (fused): per (coil,ky), 320 threads = 5 waves. 2 barriers total.
//   fwd : wave w register-FFTs row ain=w (coalesced float2 reads), F->LDS
//   mix : threads 0..255 own kx = {t, t+256}; K native layout coalesced,
//         XCD-pinned L2 reuse; G written in place (per-thread kx ownership)
//   inv : wave w register-IFFTs ao=w (lh=sig -> natural out), row stores
// LDS: F 20.5K + scratch 23K = 43.5K -> 3 blocks/CU = 15 waves/CU.
// ---------------------------------------------------------------------------
__global__ void __launch_bounds__(320) k_colfmc(const float* __restrict__ kr,
                                                const float* __restrict__ ki) {
    __shared__ float FRe[A_][512], FIm[A_][512];
    __shared__ float shR[A_][576], shI[A_][576];
    int b = blockIdx.x;
    int xcd = b & 7, s = b >> 3;          // bijective XCD-cluster swizzle
    int v = s / 96, wv = s % 96;
    int u = xcd + (v << 3);               // ky-octet 0..63
    int coil = wv % C_;
    int ky = (u << 3) + (wv / C_);
    int t = threadIdx.x;
    int w = t >> 6, L = t & 63;
    int sig = ((L & 7) << 3) | (L >> 3);
    float* sre = shR[w]; float* sim = shI[w];

    // ---- forward: wave w handles ain = w ----
    {
        const float2* row = g_bufA + (size_t)(coil * A_ + w) * 131072 +
                            ((size_t)ky << 8);
        float vr[8], vi[8];
        #pragma unroll
        for (int r = 0; r < 8; ++r) { vr[r] = 0.f; vi[r] = 0.f; }
        #pragma unroll
        for (int r = 2; r < 6; ++r) {     // x5 = 64r + L in [128,384)
            float2 vv = row[((r - 2) << 6) + L];
            vr[r] = vv.x; vi[r] = vv.y;
        }
        wfft512<-1>(vr, vi, sre, sim, L); // out: kx = 64g + sig
        #pragma unroll
        for (int g = 0; g < 8; ++g) {
            int kx = (g << 6) + sig;
            FRe[w][kx] = vr[g]; FIm[w][kx] = vi[g];
        }
    }
    __syncthreads();

    // ---- mix: G[ao][kx] = scale * sum_ain K[ao][ain][ky][kx] * F[ain][kx] ----
    const float scale = 4.0f / 262144.0f; // OVERSAMP^2 / (Hp*Wp)
    if (t < 256) {
        size_t kyb = (size_t)ky << 9;
        #pragma unroll
        for (int h = 0; h < 2; ++h) {
            int kx = t + (h << 8);
            float fr[A_], fi[A_];
            #pragma unroll
            for (int ain = 0; ain < A_; ++ain) {
                fr[ain] = FRe[ain][kx]; fi[ain] = FIm[ain][kx];
            }
            float gr[A_], gi[A_];
            #pragma unroll
            for (int ao = 0; ao < A_; ++ao) {
                float ar = 0.f, ai = 0.f;
                #pragma unroll
                for (int ain = 0; ain < A_; ++ain) {
                    size_t idx = ((size_t)(ao * A_ + ain) << 18) + kyb + kx;
                    float kre = kr[idx], kim = ki[idx];
                    ar += kre * fr[ain] - kim * fi[ain];
                    ai += kre * fi[ain] + kim * fr[ain];
                }
                gr[ao] = scale * ar; gi[ao] = scale * ai;
            }
            #pragma unroll
            for (int ao = 0; ao < A_; ++ao) {
                FRe[ao][kx] = gr[ao]; FIm[ao][kx] = gi[ao];
            }
        }
    }
    __syncthreads();

    // ---- inverse: wave w handles ao = w; swapped in (lh=sig), natural out ----
    {
        float vr[8], vi[8];
        #pragma unroll
        for (int r = 0; r < 8; ++r) {
            int kx = (r << 6) + sig;
            vr[r] = FRe[w][kx]; vi[r] = FIm[w][kx];
        }
        wfft512<1>(vr, vi, sre, sim, sig); // natural x5 = 64g + L
        float2* oB = g_bufB + (size_t)(coil * A_ + w) * 131072 +
                     ((size_t)ky << 8);
        #pragma unroll
        for (int g = 2; g < 6; ++g)        // crop x5 in [128,384)
            oB[((g - 2) << 6) + L] = make_float2(vr[g], vi[g]);
    }
}

// ---------------------------------------------------------------------------
// Pass 3: block = (a, x-quad, coil-triplet), 256 threads. Batch-4 inverse
// ky-FFTs from bufB (L3-resident chunks), crop y, conj(mps) reduce,
// atomicAdd into planar out.
// ---------------------------------------------------------------------------
__global__ void __launch_bounds__(256) k_outfr(const float* __restrict__ mr_,
        const float* __restrict__ mi_, float* __restrict__ out, int outFloats) {
    __shared__ float AR[4][NPAD], AI[4][NPAD], BR[4][NPAD], BI[4][NPAD];
    __shared__ float2 tab[288];
    int bid = blockIdx.x;                 // 5 * 64 * 4 = 1280
    int a = bid >> 8;
    int x0 = ((bid >> 2) & 63) << 2;
    int cg = bid & 3;
    int t = threadIdx.x;
    build_tab256(tab, t);
    int xc = t & 3, yo = t >> 2;          // yo 0..63
    int xcol = x0 + xc;
    float accR[4], accI[4];
    #pragma unroll
    for (int r = 0; r < 4; ++r) { accR[r] = 0.f; accI[r] = 0.f; }
    for (int cc = 0; cc < 3; ++cc) {
        int c = cg * 3 + cc;
        const float2* src = g_bufB + (size_t)(c * A_ + a) * 131072 + xcol;
        #pragma unroll
        for (int rr = 0; rr < 8; ++rr) {  // stage 512 ky per xc
            int ky = yo + 64 * rr;
            float2 vv = src[(size_t)ky * 256];
            int p = P5(ky);
            AR[xc][p] = vv.x; AI[xc][p] = vv.y;
        }
        fftB4<1>(AR, AI, BR, BI, tab, t); // head barrier orders staging
        const float* mr = mr_ + c * 65536;
        const float* mi = mi_ + c * 65536;
        #pragma unroll
        for (int rr = 0; rr < 4; ++rr) {  // crop y5 in [128,384)
            int y = yo + 64 * rr;
            int p = P5(128 + y);
            float vx = BR[xc][p], vy = BI[xc][p];
            int idx = y * 256 + xcol;
            float mrv = mr[idx], miv = mi[idx];
            accR[rr] += vx * mrv + vy * miv;   // v * conj(m)
            accI[rr] += vy * mrv - vx * miv;
        }
    }
    #pragma unroll
    for (int rr = 0; rr < 4; ++rr) {
        int y = yo + 64 * rr;
        size_t r0 = (size_t)a * 65536 + (size_t)y * 256 + xcol;
        size_t i0 = 327680 + r0;
        if (r0 < (size_t)outFloats) atomicAdd(&out[r0], accR[rr]);
        if (i0 < (size_t)outFloats) atomicAdd(&out[i0], accI[rr]);
    }
}

// ---------------------------------------------------------------------------
extern "C" void kernel_launch(void* const* d_in, const int* in_sizes, int n_in,
                              void* d_out, int out_size, void* d_ws, size_t ws_size,
                              hipStream_t stream) {
    const float* xr = (const float*)d_in[0];
    const float* xi = (const float*)d_in[1];
    const float* mr = (const float*)d_in[2];
    const float* mi = (const float*)d_in[3];
    const float* kr = (const float*)d_in[4];
    const float* ki = (const float*)d_in[5];
    float* out = (float*)d_out;
    (void)d_ws; (void)ws_size; (void)n_in; (void)in_sizes;

    int nz = out_size < 655360 ? out_size : 655360;   // floats to zero
    k_zero  <<<256, 256, 0, stream>>>(out, nz);
    k_fft1c <<<RPG * 64, 256, 0, stream>>>(xr, xi, mr, mi);
    k_colfmc<<<C_ * 512, 320, 0, stream>>>(kr, ki);
    k_outfr <<<A_ * 256, 256, 0, stream>>>(mr, mi, out, out_size);
}